// Round 1
// baseline (256.441 us; speedup 1.0000x reference)
//
#include <hip/hip_runtime.h>

#define BB 8
#define HH 32
#define CC 2048
#define DD 128
#define KK 2
#define NSLOT 256

// ws layout (floats): [0 : 8192) psum slots (256*32), [8192 : 16384) count slots
__global__ __launch_bounds__(256) void moe_router_kernel(
    const float* __restrict__ x, const float* __restrict__ W,
    float* __restrict__ y, float* __restrict__ ws) {
  __shared__ float Xs[32][132];     // padded: bank = (4h + d) % 32
  __shared__ float Wsh[32][132];
  __shared__ double Ls[32][34];     // f64 logits
  __shared__ float Ps[32][33];      // probs (for column sums)
  __shared__ float p1s[32], p2s[32];
  __shared__ int   i1s[32], i2s[32];
  __shared__ float cntS[32];

  const int tid = threadIdx.x;
  const int bc  = blockIdx.x;
  const int b   = bc >> 11;      // / 2048
  const int c   = bc & 2047;

  const float* xbase = x + (((size_t)b * HH) * CC + c) * DD;  // + h*CC*DD + d

  // ---- Phase A: stage X_bc and W into LDS (coalesced float4) ----
  #pragma unroll
  for (int r = 0; r < 4; ++r) {
    int i  = tid + (r << 8);          // 0..1023
    int h  = i >> 5;
    int d4 = i & 31;
    float4 v = *reinterpret_cast<const float4*>(xbase + (size_t)h * CC * DD + d4 * 4);
    *reinterpret_cast<float4*>(&Xs[h][d4 * 4]) = v;
    float4 w = *reinterpret_cast<const float4*>(W + h * DD + d4 * 4);
    *reinterpret_cast<float4*>(&Wsh[h][d4 * 4]) = w;
  }
  if (tid < 32) cntS[tid] = 0.0f;
  __syncthreads();

  // ---- Phase B: logits in f64.  thread -> h = tid>>3, o = (tid&7) + 8j ----
  {
    const int h  = tid >> 3;
    const int og = tid & 7;
    double a0 = 0.0, a1 = 0.0, a2 = 0.0, a3 = 0.0;
    #pragma unroll 4
    for (int d4 = 0; d4 < 32; ++d4) {
      float4 xv = *reinterpret_cast<const float4*>(&Xs[h][d4 * 4]);
      double x0 = (double)xv.x, x1 = (double)xv.y, x2 = (double)xv.z, x3 = (double)xv.w;
      float4 w0 = *reinterpret_cast<const float4*>(&Wsh[og][d4 * 4]);
      float4 w1 = *reinterpret_cast<const float4*>(&Wsh[og + 8][d4 * 4]);
      float4 w2 = *reinterpret_cast<const float4*>(&Wsh[og + 16][d4 * 4]);
      float4 w3 = *reinterpret_cast<const float4*>(&Wsh[og + 24][d4 * 4]);
      a0 += x0 * (double)w0.x; a0 += x1 * (double)w0.y; a0 += x2 * (double)w0.z; a0 += x3 * (double)w0.w;
      a1 += x0 * (double)w1.x; a1 += x1 * (double)w1.y; a1 += x2 * (double)w1.z; a1 += x3 * (double)w1.w;
      a2 += x0 * (double)w2.x; a2 += x1 * (double)w2.y; a2 += x2 * (double)w2.z; a2 += x3 * (double)w2.w;
      a3 += x0 * (double)w3.x; a3 += x1 * (double)w3.y; a3 += x2 * (double)w3.z; a3 += x3 * (double)w3.w;
    }
    Ls[h][og]      = a0;
    Ls[h][og + 8]  = a1;
    Ls[h][og + 16] = a2;
    Ls[h][og + 24] = a3;
  }
  __syncthreads();

  // ---- Phase C: softmax + top-2 per head (threads 0..31, one row each) ----
  if (tid < 32) {
    const int h = tid;
    double m = Ls[h][0];
    #pragma unroll
    for (int o = 1; o < 32; ++o) m = fmax(m, Ls[h][o]);
    float e[32];
    float S = 0.0f;
    #pragma unroll
    for (int o = 0; o < 32; ++o) {
      e[o] = expf((float)(Ls[h][o] - m));
      S += e[o];
    }
    const float invS = 1.0f / S;
    float b1 = -1.0f, b2 = -1.0f;
    int   j1 = 0, j2 = 0;
    #pragma unroll
    for (int o = 0; o < 32; ++o) {
      float p = e[o] * invS;
      Ps[h][o] = p;
      if (p > b1) { b2 = b1; j2 = j1; b1 = p; j1 = o; }
      else if (p > b2) { b2 = p; j2 = o; }
    }
    p1s[h] = b1; p2s[h] = b2; i1s[h] = j1; i2s[h] = j2;
    atomicAdd(&cntS[j1], 1.0f);
    atomicAdd(&cntS[j2], 1.0f);
  }
  __syncthreads();

  // ---- Phase D: aux partial sums -> spread slots in ws ----
  if (tid < 32) {
    float s = 0.0f;
    #pragma unroll
    for (int h2 = 0; h2 < 32; ++h2) s += Ps[h2][tid];
    int slot = bc & (NSLOT - 1);
    atomicAdd(&ws[slot * 32 + tid], s);
    atomicAdd(&ws[8192 + slot * 32 + tid], cntS[tid]);
  }

  // ---- Phase E: epilogue  y[h][d] = p1*X[i1][d] + p2*X[i2][d] (coalesced) ----
  float* ybase = y + (((size_t)b * HH) * CC + c) * DD;
  #pragma unroll
  for (int r = 0; r < 4; ++r) {
    int i  = tid + (r << 8);
    int h  = i >> 5;
    int d4 = i & 31;
    int j1 = i1s[h], j2 = i2s[h];
    float q1 = p1s[h], q2 = p2s[h];
    float4 A  = *reinterpret_cast<const float4*>(&Xs[j1][d4 * 4]);
    float4 Bv = *reinterpret_cast<const float4*>(&Xs[j2][d4 * 4]);
    float4 o4;
    o4.x = q1 * A.x + q2 * Bv.x;
    o4.y = q1 * A.y + q2 * Bv.y;
    o4.z = q1 * A.z + q2 * Bv.z;
    o4.w = q1 * A.w + q2 * Bv.w;
    *reinterpret_cast<float4*>(ybase + (size_t)h * CC * DD + d4 * 4) = o4;
  }
}

__global__ __launch_bounds__(256) void finalize_kernel(const float* __restrict__ ws,
                                                       float* __restrict__ out_aux) {
  __shared__ double redP[8][32];
  __shared__ double redC[8][32];
  const int o = threadIdx.x & 31;
  const int g = threadIdx.x >> 5;
  double sp = 0.0, sc = 0.0;
  for (int s = g; s < NSLOT; s += 8) {
    sp += (double)ws[s * 32 + o];
    sc += (double)ws[8192 + s * 32 + o];
  }
  redP[g][o] = sp;
  redC[g][o] = sc;
  __syncthreads();
  if (threadIdx.x == 0) {
    double aux = 0.0;
    const double nrows  = (double)BB * HH * CC;        // 524288
    const double ntotal = nrows * (double)KK;          // 2097152
    for (int oo = 0; oo < 32; ++oo) {
      double tp = 0.0, tc = 0.0;
      for (int gg = 0; gg < 8; ++gg) { tp += redP[gg][oo]; tc += redC[gg][oo]; }
      aux += (tp / nrows) * (tc / ntotal);
    }
    out_aux[0] = (float)(0.01 * 32.0 * aux);
  }
}

extern "C" void kernel_launch(void* const* d_in, const int* in_sizes, int n_in,
                              void* d_out, int out_size, void* d_ws, size_t ws_size,
                              hipStream_t stream) {
  const float* x = (const float*)d_in[0];
  const float* W = (const float*)d_in[1];
  float* y  = (float*)d_out;
  float* ws = (float*)d_ws;

  // zero the 64 KB of aux accumulation slots every call (graph-capture safe)
  hipMemsetAsync(d_ws, 0, 16384 * sizeof(float), stream);

  moe_router_kernel<<<BB * CC, 256, 0, stream>>>(x, W, y, ws);
  finalize_kernel<<<1, 256, 0, stream>>>(ws, y + (size_t)BB * HH * CC * DD);
}

// Round 2
// 247.643 us; speedup vs baseline: 1.0355x; 1.0355x over previous
//
#include <hip/hip_runtime.h>

#define NSLOT 256

typedef double dbl4 __attribute__((ext_vector_type(4)));

// wd[(d4*32 + o)*4 + k] = W[o][d4*4 + k]  (f64, chunk-transposed for scalar loads)
__global__ __launch_bounds__(256) void convert_w_kernel(const float* __restrict__ W,
                                                        double* __restrict__ wd) {
  int i = blockIdx.x * 256 + threadIdx.x;   // 0..4095
  int d4 = i >> 7;
  int o  = (i >> 2) & 31;
  int k  = i & 3;
  wd[i] = (double)W[(o << 7) + (d4 << 2) + k];
}

// ws layout: floats [0:8192) prob psum slots, [8192:16384) count slots; byte 65536+: W-f64 (32KB)
__global__ __launch_bounds__(256, 3) void moe_router_kernel(
    const float* __restrict__ x, const double* __restrict__ wd,
    float* __restrict__ y, float* __restrict__ ws) {
  __shared__ float  Xs[64][129];    // 64 rows (2 tokens x 32 heads), +1 dword pad
  __shared__ double Lg[64][33];     // f64 logits
  __shared__ float  p1s[64], p2s[64];
  __shared__ int    idx12[64];
  __shared__ float  cntS[32];

  const int tid = threadIdx.x;
  const int l   = tid & 63;                                  // lane = row
  const int wu  = __builtin_amdgcn_readfirstlane(tid >> 6);  // wave id -> o-block
  const int bc  = blockIdx.x;                                // 0..8191
  const int b   = bc >> 10;
  const int c0  = (bc & 1023) << 1;                          // 2 tokens per block

  const float* xb = x + ((size_t)b * 32 * 2048 + c0) * 128;

  // ---- stage X: 64 rows x 128 floats, coalesced float4 ----
  #pragma unroll
  for (int rep = 0; rep < 8; ++rep) {
    int i   = (rep << 8) + tid;        // 0..2047
    int row = i >> 5, d4 = i & 31;
    int h = row & 31, t = row >> 5;
    float4 v = *reinterpret_cast<const float4*>(xb + ((size_t)h * 2048 + t) * 128 + (d4 << 2));
    *reinterpret_cast<float4*>(&Xs[row][d4 << 2]) = v;
  }
  if (tid < 32) cntS[tid] = 0.0f;
  __syncthreads();

  // ---- phase B: 8 f64 dots per lane; W streamed via scalar loads (wave-uniform) ----
  double acc[8] = {0, 0, 0, 0, 0, 0, 0, 0};
  const dbl4* __restrict__ wv4 = reinterpret_cast<const dbl4*>(wd);
  #pragma unroll 2
  for (int d4 = 0; d4 < 32; ++d4) {
    float4 xv = *reinterpret_cast<const float4*>(&Xs[l][d4 << 2]);
    double x0 = (double)xv.x, x1 = (double)xv.y, x2 = (double)xv.z, x3 = (double)xv.w;
    const dbl4* wc = wv4 + (d4 << 5) + (wu << 3);   // 8 o-rows, wave-uniform
    #pragma unroll
    for (int j = 0; j < 8; ++j) {
      dbl4 wj = wc[j];
      acc[j] = fma(x0, wj[0], acc[j]);
      acc[j] = fma(x1, wj[1], acc[j]);
      acc[j] = fma(x2, wj[2], acc[j]);
      acc[j] = fma(x3, wj[3], acc[j]);
    }
  }
  #pragma unroll
  for (int j = 0; j < 8; ++j) Lg[l][(wu << 3) + j] = acc[j];
  __syncthreads();

  // ---- phase C: softmax + top-2 per row (each wave redundantly handles row l) ----
  double b1 = -1.0e300, b2 = -1.0e300;
  int    j1 = 0, j2 = 0;
  float  S  = 0.0f;
  #pragma unroll
  for (int o = 0; o < 32; ++o) {
    double lv = Lg[l][o];
    S += __expf((float)lv);
    if (lv > b1)      { b2 = b1; j2 = j1; b1 = lv; j1 = o; }
    else if (lv > b2) { b2 = lv; j2 = o; }
  }
  const float invS = 1.0f / S;

  // per-wave slice of probs for the aux column sums
  float ps[8];
  #pragma unroll
  for (int j = 0; j < 8; ++j)
    ps[j] = __expf((float)Lg[l][(wu << 3) + j]) * invS;

  if (wu == 0) {
    p1s[l] = __expf((float)b1) * invS;
    p2s[l] = __expf((float)b2) * invS;
    idx12[l] = j1 | (j2 << 8);
    atomicAdd(&cntS[j1], 1.0f);
    atomicAdd(&cntS[j2], 1.0f);
  }

  // shuffle-tree sum of ps over the 64 rows
  #pragma unroll
  for (int m = 1; m < 64; m <<= 1) {
    #pragma unroll
    for (int j = 0; j < 8; ++j) ps[j] += __shfl_xor(ps[j], m, 64);
  }
  if (l == 0) {
    const int slot = (bc & (NSLOT - 1)) << 5;
    #pragma unroll
    for (int j = 0; j < 8; ++j) atomicAdd(&ws[slot + (wu << 3) + j], ps[j]);
  }
  __syncthreads();

  if (tid < 32) atomicAdd(&ws[8192 + ((bc & (NSLOT - 1)) << 5) + tid], cntS[tid]);

  // ---- epilogue: y[row][d] = p1*X[t][i1][d] + p2*X[t][i2][d] ----
  float* yb = y + ((size_t)b * 32 * 2048 + c0) * 128;
  #pragma unroll
  for (int rep = 0; rep < 8; ++rep) {
    int i   = (rep << 8) + tid;
    int row = i >> 5, d4 = i & 31;
    int h = row & 31, t = row >> 5;
    int pk = idx12[row];
    int i1 = pk & 255, i2 = pk >> 8;
    float q1 = p1s[row], q2 = p2s[row];
    const float4 A  = *reinterpret_cast<const float4*>(&Xs[(t << 5) + i1][d4 << 2]);
    const float4 Bv = *reinterpret_cast<const float4*>(&Xs[(t << 5) + i2][d4 << 2]);
    float4 o4;
    o4.x = q1 * A.x + q2 * Bv.x;
    o4.y = q1 * A.y + q2 * Bv.y;
    o4.z = q1 * A.z + q2 * Bv.z;
    o4.w = q1 * A.w + q2 * Bv.w;
    *reinterpret_cast<float4*>(yb + ((size_t)h * 2048 + t) * 128 + (d4 << 2)) = o4;
  }
}

__global__ __launch_bounds__(256) void finalize_kernel(const float* __restrict__ ws,
                                                       float* __restrict__ out_aux) {
  __shared__ double redP[8][32];
  __shared__ double redC[8][32];
  const int o = threadIdx.x & 31;
  const int g = threadIdx.x >> 5;
  double sp = 0.0, sc = 0.0;
  for (int s = g; s < NSLOT; s += 8) {
    sp += (double)ws[s * 32 + o];
    sc += (double)ws[8192 + s * 32 + o];
  }
  redP[g][o] = sp;
  redC[g][o] = sc;
  __syncthreads();
  if (threadIdx.x == 0) {
    double aux = 0.0;
    const double nrows  = 524288.0;          // B*H*C
    const double ntotal = 1048576.0;         // nrows * K
    for (int oo = 0; oo < 32; ++oo) {
      double tp = 0.0, tc = 0.0;
      for (int gg = 0; gg < 8; ++gg) { tp += redP[gg][oo]; tc += redC[gg][oo]; }
      aux += (tp / nrows) * (tc / ntotal);
    }
    out_aux[0] = (float)(0.01 * 32.0 * aux);
  }
}

extern "C" void kernel_launch(void* const* d_in, const int* in_sizes, int n_in,
                              void* d_out, int out_size, void* d_ws, size_t ws_size,
                              hipStream_t stream) {
  const float* x = (const float*)d_in[0];
  const float* W = (const float*)d_in[1];
  float*  y  = (float*)d_out;
  float*  ws = (float*)d_ws;
  double* wd = (double*)((char*)d_ws + 65536);

  hipMemsetAsync(d_ws, 0, 16384 * sizeof(float), stream);
  convert_w_kernel<<<16, 256, 0, stream>>>(W, wd);
  moe_router_kernel<<<8192, 256, 0, stream>>>(x, wd, y, ws);
  finalize_kernel<<<1, 256, 0, stream>>>(ws, y + (size_t)8 * 32 * 2048 * 128);
}

// Round 4
// 194.039 us; speedup vs baseline: 1.3216x; 1.2763x over previous
//
#include <hip/hip_runtime.h>

#define NSLOT 256

typedef double dbl4 __attribute__((ext_vector_type(4)));
typedef float  f32x4 __attribute__((ext_vector_type(4)));

// wd[(d4*32 + o)*4 + k] = W[o][d4*4 + k]  (f64, chunk-transposed for scalar loads)
__global__ __launch_bounds__(256) void convert_w_kernel(const float* __restrict__ W,
                                                        double* __restrict__ wd) {
  int i = blockIdx.x * 256 + threadIdx.x;   // 0..4095
  int d4 = i >> 7;
  int o  = (i >> 2) & 31;
  int k  = i & 3;
  wd[i] = (double)W[(o << 7) + (d4 << 2) + k];
}

// ws layout: floats [0:8192) prob psum slots, [8192:16384) count slots; byte 65536+: W-f64 (32KB)
__global__ __launch_bounds__(256, 4) void moe_router_kernel(
    const float* __restrict__ x, const double* __restrict__ wd,
    float* __restrict__ y, float* __restrict__ ws) {
  // Xs: 64 rows x 32 chunks of 16B, chunk XOR-swizzled: phys p holds logical d4 = p ^ (row&31)
  __shared__ float  Xs[64 * 128];
  __shared__ double m1s[4][64];
  __shared__ double m2s[4][64];
  __shared__ int    jps[4][64];
  __shared__ float  sumS[4][64];

  const int tid = threadIdx.x;
  const int l   = tid & 63;                                  // lane (= row in phase B/C)
  const int wu  = __builtin_amdgcn_readfirstlane(tid >> 6);  // wave id -> o-block
  const int bc  = blockIdx.x;                                // 0..8191
  const int b   = bc >> 10;
  const int c0  = (bc & 1023) << 1;                          // 2 tokens per block

  const float* xb = x + ((size_t)b * 32 * 2048 + c0) * 128;

  // ---- stage X via global_load_lds (linear LDS dest, pre-swizzled global src) ----
  {
    auto ldsX = (__attribute__((address_space(3))) char*)Xs;
    #pragma unroll
    for (int rep = 0; rep < 8; ++rep) {
      int i   = (rep << 8) + tid;           // 0..2047 = linear 16B chunk index
      int row = i >> 5;                     // 0..63
      int p   = i & 31;                     // physical chunk
      int h   = row & 31, t = row >> 5;
      int d4  = p ^ (row & 31);             // logical chunk stored at p
      const float* src = xb + ((size_t)h * 2048 + t) * 128 + (d4 << 2);
      __builtin_amdgcn_global_load_lds(
          (const __attribute__((address_space(1))) void*)src,
          (__attribute__((address_space(3))) void*)(ldsX + (size_t)i * 16),
          16, 0, 0);
    }
  }
  __syncthreads();

  // ---- phase B: 8 f64 dots per lane (row = l); W via wave-uniform scalar loads ----
  double acc[8] = {0, 0, 0, 0, 0, 0, 0, 0};
  const dbl4* __restrict__ wv4 = reinterpret_cast<const dbl4*>(wd);
  const int rsw = l & 31;
  #pragma unroll 2
  for (int d4 = 0; d4 < 32; ++d4) {
    float4 xv = *reinterpret_cast<const float4*>(&Xs[(l << 7) + ((d4 ^ rsw) << 2)]);
    double x0 = (double)xv.x, x1 = (double)xv.y, x2 = (double)xv.z, x3 = (double)xv.w;
    const dbl4* wc = wv4 + (d4 << 5) + (wu << 3);
    #pragma unroll
    for (int j = 0; j < 8; ++j) {
      dbl4 wj = wc[j];
      acc[j] = fma(x0, wj[0], acc[j]);
      acc[j] = fma(x1, wj[1], acc[j]);
      acc[j] = fma(x2, wj[2], acc[j]);
      acc[j] = fma(x3, wj[3], acc[j]);
    }
  }

  // ---- local top-2 + exp-sum over this wave's 8 o's (in registers) ----
  double m1 = acc[0], m2 = -1.0e300;
  int    j1 = 0, j2 = 0;
  #pragma unroll
  for (int j = 1; j < 8; ++j) {
    double v = acc[j];
    if (v > m1)      { m2 = m1; j2 = j1; m1 = v; j1 = j; }
    else if (v > m2) { m2 = v; j2 = j; }
  }
  float e[8];
  float sloc = 0.0f;
  #pragma unroll
  for (int j = 0; j < 8; ++j) { e[j] = __expf((float)(acc[j] - m1)); sloc += e[j]; }

  m1s[wu][l]  = m1;
  m2s[wu][l]  = m2;
  jps[wu][l]  = (j1 + (wu << 3)) | ((j2 + (wu << 3)) << 8);
  sumS[wu][l] = sloc;
  __syncthreads();

  // ---- merge the 4 per-wave summaries (redundant in every wave; lane = row) ----
  double M = -1.0e300, g2 = -1.0e300;
  int g1i = 0, g2i = 0;
  #pragma unroll
  for (int w = 0; w < 4; ++w) {
    double a  = m1s[w][l];
    double bb = m2s[w][l];
    int    jp = jps[w][l];
    if (a > M)       { g2 = M; g2i = g1i; M = a; g1i = jp & 255; }
    else if (a > g2) { g2 = a; g2i = jp & 255; }
    if (bb > g2)     { g2 = bb; g2i = (jp >> 8) & 255; }
  }
  float S = 0.0f;
  #pragma unroll
  for (int w = 0; w < 4; ++w)
    S += sumS[w][l] * __expf((float)(m1s[w][l] - M));
  const float invS = 1.0f / S;
  const float p1 = invS;                              // exp(M-M)/S
  const float p2 = __expf((float)(g2 - M)) * invS;
  const int   jpack = g1i | (g2i << 8);

  // ---- aux prob column-sums: rescale own-wave exps, shuffle-tree over 64 rows ----
  {
    const float f = __expf((float)(m1 - M)) * invS;
    float ps[8];
    #pragma unroll
    for (int j = 0; j < 8; ++j) ps[j] = e[j] * f;
    #pragma unroll
    for (int m = 1; m < 64; m <<= 1) {
      #pragma unroll
      for (int j = 0; j < 8; ++j) ps[j] += __shfl_xor(ps[j], m, 64);
    }
    const int slot = (bc & (NSLOT - 1)) << 5;
    if (l == 0) {
      #pragma unroll
      for (int j = 0; j < 8; ++j) atomicAdd(&ws[slot + (wu << 3) + j], ps[j]);
    }
    // counts via ballot (wave 0 only)
    if (wu == 0) {
      float cnt = 0.0f;
      #pragma unroll
      for (int o = 0; o < 32; ++o) {
        float c = (float)(__popcll(__ballot(g1i == o)) + __popcll(__ballot(g2i == o)));
        if (l == o) cnt = c;
      }
      if (l < 32) atomicAdd(&ws[8192 + slot + l], cnt);
    }
  }

  // ---- epilogue: coalesced y writes; p/j broadcast via shuffle (no 3rd barrier) ----
  float* yb = y + ((size_t)b * 32 * 2048 + c0) * 128;
  #pragma unroll
  for (int rep = 0; rep < 8; ++rep) {
    int i   = (rep << 8) + tid;
    int row = i >> 5;                    // row whose chunk this thread writes
    int d4  = i & 31;                    // logical chunk
    float q1 = __shfl(p1, row, 64);
    float q2 = __shfl(p2, row, 64);
    int   jp = __shfl(jpack, row, 64);
    int i1 = jp & 255, i2 = (jp >> 8) & 255;
    int t = row >> 5, h = row & 31;
    const float4 A  = *reinterpret_cast<const float4*>(
        &Xs[(((t << 5) + i1) << 7) + ((d4 ^ i1) << 2)]);
    const float4 Bv = *reinterpret_cast<const float4*>(
        &Xs[(((t << 5) + i2) << 7) + ((d4 ^ i2) << 2)]);
    f32x4 o4;
    o4.x = q1 * A.x + q2 * Bv.x;
    o4.y = q1 * A.y + q2 * Bv.y;
    o4.z = q1 * A.z + q2 * Bv.z;
    o4.w = q1 * A.w + q2 * Bv.w;
    __builtin_nontemporal_store(o4,
        reinterpret_cast<f32x4*>(yb + ((size_t)h * 2048 + t) * 128 + (d4 << 2)));
  }
}

__global__ __launch_bounds__(256) void finalize_kernel(const float* __restrict__ ws,
                                                       float* __restrict__ out_aux) {
  __shared__ double redP[8][32];
  __shared__ double redC[8][32];
  const int o = threadIdx.x & 31;
  const int g = threadIdx.x >> 5;
  double sp = 0.0, sc = 0.0;
  for (int s = g; s < NSLOT; s += 8) {
    sp += (double)ws[s * 32 + o];
    sc += (double)ws[8192 + s * 32 + o];
  }
  redP[g][o] = sp;
  redC[g][o] = sc;
  __syncthreads();
  if (threadIdx.x == 0) {
    double aux = 0.0;
    const double nrows  = 524288.0;          // B*H*C
    const double ntotal = 1048576.0;         // nrows * K
    for (int oo = 0; oo < 32; ++oo) {
      double tp = 0.0, tc = 0.0;
      for (int gg = 0; gg < 8; ++gg) { tp += redP[gg][oo]; tc += redC[gg][oo]; }
      aux += (tp / nrows) * (tc / ntotal);
    }
    out_aux[0] = (float)(0.01 * 32.0 * aux);
  }
}

extern "C" void kernel_launch(void* const* d_in, const int* in_sizes, int n_in,
                              void* d_out, int out_size, void* d_ws, size_t ws_size,
                              hipStream_t stream) {
  const float* x = (const float*)d_in[0];
  const float* W = (const float*)d_in[1];
  float*  y  = (float*)d_out;
  float*  ws = (float*)d_ws;
  double* wd = (double*)((char*)d_ws + 65536);

  (void)hipMemsetAsync(d_ws, 0, 16384 * sizeof(float), stream);
  convert_w_kernel<<<16, 256, 0, stream>>>(W, wd);
  moe_router_kernel<<<8192, 256, 0, stream>>>(x, wd, y, ws);
  finalize_kernel<<<1, 256, 0, stream>>>(ws, y + (size_t)8 * 32 * 2048 * 128);
}

// Round 5
// 175.820 us; speedup vs baseline: 1.4585x; 1.1036x over previous
//
#include <hip/hip_runtime.h>

#define NSLOT 256

typedef double dbl4 __attribute__((ext_vector_type(4)));
typedef float  f32x4 __attribute__((ext_vector_type(4)));

// prep: zero the 16384 aux accumulation floats; convert W to f64 chunk-transposed:
// wd[(d4*32 + o)*4 + k] = W[o][d4*4 + k]
__global__ __launch_bounds__(256) void prep_kernel(const float* __restrict__ W,
                                                   double* __restrict__ wd,
                                                   float* __restrict__ ws) {
  int i = blockIdx.x * 256 + threadIdx.x;   // grid 64 -> 16384 threads
  ws[i] = 0.0f;
  if (i < 4096) {
    int d4 = i >> 7;
    int o  = (i >> 2) & 31;
    int k  = i & 3;
    wd[i] = (double)W[(o << 7) + (d4 << 2) + k];
  }
}

// ws layout: floats [0:8192) prob psum slots, [8192:16384) count slots; byte 65536+: W-f64 (32KB)
__global__ __launch_bounds__(512, 6) void moe_router_kernel(
    const float* __restrict__ x, const double* __restrict__ wd,
    float* __restrict__ y, float* __restrict__ ws) {
  // Xs: 64 rows x 32 chunks of 16B, chunk XOR-swizzled: phys p holds logical d4 = p ^ (row&31)
  __shared__ float  Xs[64 * 128];
  __shared__ double m1s[8][64];
  __shared__ double m2s[8][64];
  __shared__ int    jps[8][64];
  __shared__ float  sumS[8][64];

  const int tid = threadIdx.x;
  const int l   = tid & 63;                                  // lane (= row in phase B/C)
  const int wu  = __builtin_amdgcn_readfirstlane(tid >> 6);  // wave id 0..7 -> o-quad
  const int bc  = blockIdx.x;                                // 0..8191
  const int b   = bc >> 10;
  const int c0  = (bc & 1023) << 1;                          // 2 tokens per block

  const float* xb = x + ((size_t)b * 32 * 2048 + c0) * 128;

  // ---- stage X via global_load_lds (linear LDS dest, pre-swizzled global src) ----
  {
    auto ldsX = (__attribute__((address_space(3))) char*)Xs;
    #pragma unroll
    for (int rep = 0; rep < 4; ++rep) {
      int i   = (rep << 9) + tid;           // 0..2047 = linear 16B chunk index
      int row = i >> 5;                     // 0..63
      int p   = i & 31;                     // physical chunk
      int h   = row & 31, t = row >> 5;
      int d4  = p ^ (row & 31);             // logical chunk stored at p
      const float* src = xb + ((size_t)h * 2048 + t) * 128 + (d4 << 2);
      __builtin_amdgcn_global_load_lds(
          (const __attribute__((address_space(1))) void*)src,
          (__attribute__((address_space(3))) void*)(ldsX + (size_t)i * 16),
          16, 0, 0);
    }
  }
  __syncthreads();

  // ---- phase B: 4 f64 dots per lane (row = l); W via wave-uniform scalar loads ----
  double a0 = 0.0, a1 = 0.0, a2 = 0.0, a3 = 0.0;
  const dbl4* __restrict__ wv4 = reinterpret_cast<const dbl4*>(wd);
  const int rsw  = l & 31;
  const int base = l << 7;
  float4 xv = *reinterpret_cast<const float4*>(&Xs[base + (rsw << 2)]);  // chunk 0^rsw
  #pragma unroll 4
  for (int d4 = 0; d4 < 32; ++d4) {
    // branch-free prefetch of next chunk (wraps to 0 at the end, harmless)
    float4 xn = *reinterpret_cast<const float4*>(
        &Xs[base + ((((d4 + 1) & 31) ^ rsw) << 2)]);
    const dbl4* wc = wv4 + (d4 << 5) + (wu << 2);
    dbl4 w0 = wc[0], w1 = wc[1], w2 = wc[2], w3 = wc[3];
    double x0 = (double)xv.x, x1 = (double)xv.y, x2 = (double)xv.z, x3 = (double)xv.w;
    a0 = fma(x0, w0[0], a0); a0 = fma(x1, w0[1], a0);
    a0 = fma(x2, w0[2], a0); a0 = fma(x3, w0[3], a0);
    a1 = fma(x0, w1[0], a1); a1 = fma(x1, w1[1], a1);
    a1 = fma(x2, w1[2], a1); a1 = fma(x3, w1[3], a1);
    a2 = fma(x0, w2[0], a2); a2 = fma(x1, w2[1], a2);
    a2 = fma(x2, w2[2], a2); a2 = fma(x3, w2[3], a2);
    a3 = fma(x0, w3[0], a3); a3 = fma(x1, w3[1], a3);
    a3 = fma(x2, w3[2], a3); a3 = fma(x3, w3[3], a3);
    xv = xn;
  }

  // ---- local top-2 + exp-sum over this wave's 4 o's (in registers) ----
  double acc[4] = {a0, a1, a2, a3};
  double m1 = acc[0], m2 = -1.0e300;
  int    j1 = 0, j2 = 0;
  #pragma unroll
  for (int j = 1; j < 4; ++j) {
    double v = acc[j];
    if (v > m1)      { m2 = m1; j2 = j1; m1 = v; j1 = j; }
    else if (v > m2) { m2 = v; j2 = j; }
  }
  float e[4];
  float sloc = 0.0f;
  #pragma unroll
  for (int j = 0; j < 4; ++j) { e[j] = __expf((float)(acc[j] - m1)); sloc += e[j]; }

  m1s[wu][l]  = m1;
  m2s[wu][l]  = m2;
  jps[wu][l]  = (j1 + (wu << 2)) | ((j2 + (wu << 2)) << 8);
  sumS[wu][l] = sloc;
  __syncthreads();

  // ---- merge the 8 per-wave summaries (redundant in every wave; lane = row) ----
  double M = -1.0e300, g2 = -1.0e300;
  int g1i = 0, g2i = 0;
  #pragma unroll
  for (int w = 0; w < 8; ++w) {
    double a  = m1s[w][l];
    double bb = m2s[w][l];
    int    jp = jps[w][l];
    if (a > M)       { g2 = M; g2i = g1i; M = a; g1i = jp & 255; }
    else if (a > g2) { g2 = a; g2i = jp & 255; }
    if (bb > g2)     { g2 = bb; g2i = (jp >> 8) & 255; }
  }
  float S = 0.0f;
  #pragma unroll
  for (int w = 0; w < 8; ++w)
    S += sumS[w][l] * __expf((float)(m1s[w][l] - M));
  const float invS = 1.0f / S;
  const float p1 = invS;                              // exp(M-M)/S
  const float p2 = __expf((float)(g2 - M)) * invS;
  const int   jpack = g1i | (g2i << 8);

  // ---- aux prob column-sums: rescale own-wave exps, shuffle-tree over 64 rows ----
  {
    const float f = __expf((float)(m1 - M)) * invS;
    float ps[4];
    #pragma unroll
    for (int j = 0; j < 4; ++j) ps[j] = e[j] * f;
    #pragma unroll
    for (int m = 1; m < 64; m <<= 1) {
      #pragma unroll
      for (int j = 0; j < 4; ++j) ps[j] += __shfl_xor(ps[j], m, 64);
    }
    const int slot = (bc & (NSLOT - 1)) << 5;
    if (l == 0) {
      #pragma unroll
      for (int j = 0; j < 4; ++j) atomicAdd(&ws[slot + (wu << 2) + j], ps[j]);
    }
    // counts via ballot (wave 0 only)
    if (wu == 0) {
      float cnt = 0.0f;
      #pragma unroll
      for (int o = 0; o < 32; ++o) {
        float c = (float)(__popcll(__ballot(g1i == o)) + __popcll(__ballot(g2i == o)));
        if (l == o) cnt = c;
      }
      if (l < 32) atomicAdd(&ws[8192 + slot + l], cnt);
    }
  }

  // ---- epilogue: coalesced y writes; p/j broadcast via shuffle (no 3rd barrier) ----
  float* yb = y + ((size_t)b * 32 * 2048 + c0) * 128;
  #pragma unroll
  for (int rep = 0; rep < 4; ++rep) {
    int i   = (rep << 9) + tid;
    int row = i >> 5;                    // row whose chunk this thread writes
    int d4  = i & 31;                    // logical chunk
    float q1 = __shfl(p1, row, 64);
    float q2 = __shfl(p2, row, 64);
    int   jp = __shfl(jpack, row, 64);
    int i1 = jp & 255, i2 = (jp >> 8) & 255;
    int t = row >> 5, h = row & 31;
    const float4 A  = *reinterpret_cast<const float4*>(
        &Xs[(((t << 5) + i1) << 7) + ((d4 ^ i1) << 2)]);
    const float4 Bv = *reinterpret_cast<const float4*>(
        &Xs[(((t << 5) + i2) << 7) + ((d4 ^ i2) << 2)]);
    f32x4 o4;
    o4.x = q1 * A.x + q2 * Bv.x;
    o4.y = q1 * A.y + q2 * Bv.y;
    o4.z = q1 * A.z + q2 * Bv.z;
    o4.w = q1 * A.w + q2 * Bv.w;
    __builtin_nontemporal_store(o4,
        reinterpret_cast<f32x4*>(yb + ((size_t)h * 2048 + t) * 128 + (d4 << 2)));
  }
}

__global__ __launch_bounds__(256) void finalize_kernel(const float* __restrict__ ws,
                                                       float* __restrict__ out_aux) {
  __shared__ double redP[8][32];
  __shared__ double redC[8][32];
  const int o = threadIdx.x & 31;
  const int g = threadIdx.x >> 5;
  double sp = 0.0, sc = 0.0;
  for (int s = g; s < NSLOT; s += 8) {
    sp += (double)ws[s * 32 + o];
    sc += (double)ws[8192 + s * 32 + o];
  }
  redP[g][o] = sp;
  redC[g][o] = sc;
  __syncthreads();
  if (threadIdx.x == 0) {
    double aux = 0.0;
    const double nrows  = 524288.0;          // B*H*C
    const double ntotal = 1048576.0;         // nrows * K
    for (int oo = 0; oo < 32; ++oo) {
      double tp = 0.0, tc = 0.0;
      for (int gg = 0; gg < 8; ++gg) { tp += redP[gg][oo]; tc += redC[gg][oo]; }
      aux += (tp / nrows) * (tc / ntotal);
    }
    out_aux[0] = (float)(0.01 * 32.0 * aux);
  }
}

extern "C" void kernel_launch(void* const* d_in, const int* in_sizes, int n_in,
                              void* d_out, int out_size, void* d_ws, size_t ws_size,
                              hipStream_t stream) {
  const float* x = (const float*)d_in[0];
  const float* W = (const float*)d_in[1];
  float*  y  = (float*)d_out;
  float*  ws = (float*)d_ws;
  double* wd = (double*)((char*)d_ws + 65536);

  prep_kernel<<<64, 256, 0, stream>>>(W, wd, ws);
  moe_router_kernel<<<8192, 512, 0, stream>>>(x, wd, y, ws);
  finalize_kernel<<<1, 256, 0, stream>>>(ws, y + (size_t)8 * 32 * 2048 * 128);
}